// Round 1
// baseline (427.449 us; speedup 1.0000x reference)
//
#include <hip/hip_runtime.h>

#define NTH 256
#define B_TOTAL 32768

// ---------------- LDS layout (floats) ----------------
enum : int {
  OFF_WH0 = 0,       // 96  (3,32)
  OFF_WY0 = 96,      // 96
  OFF_WYU0 = 192,    // 9   (3,3)
  OFF_WU0 = 201,     // 96
  OFF_WH1 = 297,     // 1024
  OFF_WZ1R = 1321,   // 1024 relu(w_z1)
  OFF_WZU1 = 2345,   // 1024
  OFF_WY1 = 3369,    // 96
  OFF_WYU1 = 3465,   // 96  (32,3)
  OFF_WU1 = 3561,    // 1024
  OFF_WH2 = 4585,    // 1024
  OFF_WZ2R = 5609,   // 1024
  OFF_WZU2 = 6633,   // 1024
  OFF_WY2 = 7657,    // 96
  OFF_WYU2 = 7753,   // 96
  OFF_WU2 = 7849,    // 1024
  OFF_WZOR = 8873,   // 32 relu(w_z_out)
  OFF_WZUO = 8905,   // 1024
  OFF_WYO = 9929,    // 3
  OFF_WYUO = 9932,   // 96
  OFF_WUO = 10028,   // 32
  OFF_FC1 = 10060,   // 96 (32,3) row-major [j][k]
  OFF_FC2T = 10156,  // 1024 transposed: [i][j] = fc2_w[j][i]
  OFF_FC3T = 11180,  // 1024 transposed
  OFF_FC4 = 12204,   // 32
  OFF_BY0 = 12236,   // 3
  OFF_BH0 = 12239,   // 32
  OFF_B0 = 12271,    // 32
  OFF_BH1 = 12303,   // 32
  OFF_BY1 = 12335,   // 3
  OFF_BZ1 = 12338,   // 32
  OFF_B1 = 12370,    // 32
  OFF_BH2 = 12402,   // 32
  OFF_BZ2 = 12434,   // 32
  OFF_BY2 = 12466,   // 3
  OFF_B2 = 12469,    // 32
  OFF_BZO = 12501,   // 32
  OFF_BYO = 12533,   // 3
  OFF_BOUT = 12536,  // 1
  OFF_FC1B = 12537,  // 32
  OFF_FC2B = 12569,  // 32
  OFF_FC3B = 12601,  // 32
  OFF_FC4B = 12633,  // 1
  LDS_FLOATS = 12634
};

struct Ptrs { const float* p[44]; };

// jet with full 2nd order y/cross state:
// c[0]=v, c[1..3]=dy, c[4..6]=dq, c[7..12]=d2yy sym {00,01,02,11,12,22},
// c[13..21]=d2ydq row-major [a*3+b]
struct V22 { float c[22]; };
// q-only jet: c[0]=v, c[1..3]=dq
struct V4q { float c[4]; };

__device__ __forceinline__ float spf(float x) {
  return fmaxf(x, 0.0f) + __logf(1.0f + __expf(-fabsf(x)));
}
__device__ __forceinline__ float sigf(float x) {
  return __fdividef(1.0f, 1.0f + __expf(-x));
}
__device__ __forceinline__ float bc(float v, int i) { return __shfl(v, i, 32); }

__device__ __forceinline__ V22 spchain22(const V22& A) {
  V22 Z;
  float s = sigf(A.c[0]);
  float d = s * (1.0f - s);
  Z.c[0] = spf(A.c[0]);
#pragma unroll
  for (int a = 0; a < 3; ++a) Z.c[1 + a] = s * A.c[1 + a];
#pragma unroll
  for (int b = 0; b < 3; ++b) Z.c[4 + b] = s * A.c[4 + b];
  const int pa[6] = {0, 0, 0, 1, 1, 2}, pb[6] = {0, 1, 2, 1, 2, 2};
#pragma unroll
  for (int t = 0; t < 6; ++t)
    Z.c[7 + t] = s * A.c[7 + t] + d * A.c[1 + pa[t]] * A.c[1 + pb[t]];
#pragma unroll
  for (int a = 0; a < 3; ++a)
#pragma unroll
    for (int b = 0; b < 3; ++b)
      Z.c[13 + a * 3 + b] = s * A.c[13 + a * 3 + b] + d * A.c[1 + a] * A.c[4 + b];
  return Z;
}

__device__ __forceinline__ V4q sp4(const V4q& h) {
  V4q u;
  float ss = sigf(h.c[0]);
  u.c[0] = spf(h.c[0]);
  u.c[1] = ss * h.c[1];
  u.c[2] = ss * h.c[2];
  u.c[3] = ss * h.c[3];
  return u;
}

// P = Z (full jet) * S (q-only jet), elementwise product rule
__device__ __forceinline__ V22 prodZS(const V22& Z, const V4q& S) {
  V22 P;
  P.c[0] = Z.c[0] * S.c[0];
#pragma unroll
  for (int a = 0; a < 3; ++a) P.c[1 + a] = S.c[0] * Z.c[1 + a];
#pragma unroll
  for (int b = 0; b < 3; ++b) P.c[4 + b] = Z.c[0] * S.c[1 + b] + S.c[0] * Z.c[4 + b];
#pragma unroll
  for (int t = 0; t < 6; ++t) P.c[7 + t] = S.c[0] * Z.c[7 + t];
#pragma unroll
  for (int a = 0; a < 3; ++a)
#pragma unroll
    for (int b = 0; b < 3; ++b)
      P.c[13 + a * 3 + b] = S.c[0] * Z.c[13 + a * 3 + b] + Z.c[1 + a] * S.c[1 + b];
  return P;
}

// broadcast-matvec: acc[j] += sum_i p_i * W[i*32+j] on all 22 jet comps
__device__ __forceinline__ void mv22(const float* lds, int j, const V22& p, int off, V22& acc) {
#pragma unroll 4
  for (int i = 0; i < 32; ++i) {
    float w = lds[off + i * 32 + j];
#pragma unroll
    for (int k = 0; k < 22; ++k) acc.c[k] += bc(p.c[k], i) * w;
  }
}

// u-consuming stage: h += u@Wh, s += u@Wzu, w += u@Wu (per-lane col j), t[m] += u@Wyu (32->3, replicated)
__device__ __forceinline__ void stageU(const float* lds, int j, const V4q& u,
                                       int offH, int offZU, int offU, int offYU,
                                       V4q& h, V4q& s, V4q& w, V4q t[3]) {
#pragma unroll 4
  for (int i = 0; i < 32; ++i) {
    float u0 = bc(u.c[0], i), u1_ = bc(u.c[1], i), u2_ = bc(u.c[2], i), u3_ = bc(u.c[3], i);
    float wh = lds[offH + i * 32 + j], wz = lds[offZU + i * 32 + j], wu = lds[offU + i * 32 + j];
    h.c[0] += u0 * wh; h.c[1] += u1_ * wh; h.c[2] += u2_ * wh; h.c[3] += u3_ * wh;
    s.c[0] += u0 * wz; s.c[1] += u1_ * wz; s.c[2] += u2_ * wz; s.c[3] += u3_ * wz;
    w.c[0] += u0 * wu; w.c[1] += u1_ * wu; w.c[2] += u2_ * wu; w.c[3] += u3_ * wu;
#pragma unroll
    for (int m = 0; m < 3; ++m) {
      float wy = lds[offYU + i * 3 + m];
      t[m].c[0] += u0 * wy; t[m].c[1] += u1_ * wy; t[m].c[2] += u2_ * wy; t[m].c[3] += u3_ * wy;
    }
  }
}

// local (non-matvec) terms of a pre-activation: w + (y*t)@Wy  with Wy (3,32)
__device__ __forceinline__ void buildA(const float* lds, int j, const float* yv,
                                       const V4q& w, const V4q t[3], int offWY, V22& A) {
  float wy[3] = {lds[offWY + j], lds[offWY + 32 + j], lds[offWY + 64 + j]};
  A.c[0] = w.c[0] + yv[0] * t[0].c[0] * wy[0] + yv[1] * t[1].c[0] * wy[1] + yv[2] * t[2].c[0] * wy[2];
#pragma unroll
  for (int a = 0; a < 3; ++a) A.c[1 + a] = t[a].c[0] * wy[a];
#pragma unroll
  for (int b = 0; b < 3; ++b)
    A.c[4 + b] = w.c[1 + b] + yv[0] * t[0].c[1 + b] * wy[0] + yv[1] * t[1].c[1 + b] * wy[1] +
                 yv[2] * t[2].c[1 + b] * wy[2];
#pragma unroll
  for (int t6 = 0; t6 < 6; ++t6) A.c[7 + t6] = 0.0f;
#pragma unroll
  for (int a = 0; a < 3; ++a)
#pragma unroll
    for (int b = 0; b < 3; ++b) A.c[13 + a * 3 + b] = t[a].c[1 + b] * wy[a];
}

__global__ __launch_bounds__(NTH, 3) void lnn_step_kernel(Ptrs P, float* __restrict__ out) {
  __shared__ float lds[LDS_FLOATS];
  const int tid = threadIdx.x;

  // ---------------- stage weights into LDS ----------------
  {
    auto cp = [&](int idx, int off, int n) {
      const float* s = P.p[idx];
      for (int k = tid; k < n; k += NTH) lds[off + k] = s[k];
    };
    auto cpRelu = [&](int idx, int off, int n) {
      const float* s = P.p[idx];
      for (int k = tid; k < n; k += NTH) lds[off + k] = fmaxf(s[k], 0.0f);
    };
    auto cpT = [&](int idx, int off) {  // (32,32) [j][i] -> [i*32+j]
      const float* s = P.p[idx];
      for (int k = tid; k < 1024; k += NTH) {
        int r = k >> 5, c = k & 31;
        lds[off + c * 32 + r] = s[k];
      }
    };
    cp(1, OFF_WH0, 96);    cp(2, OFF_WY0, 96);    cp(3, OFF_WYU0, 9);   cp(4, OFF_WU0, 96);
    cp(5, OFF_WH1, 1024);  cpRelu(6, OFF_WZ1R, 1024); cp(7, OFF_WZU1, 1024);
    cp(8, OFF_WY1, 96);    cp(9, OFF_WYU1, 96);   cp(10, OFF_WU1, 1024);
    cp(11, OFF_WH2, 1024); cpRelu(12, OFF_WZ2R, 1024); cp(13, OFF_WZU2, 1024);
    cp(14, OFF_WY2, 96);   cp(15, OFF_WYU2, 96);  cp(16, OFF_WU2, 1024);
    cpRelu(17, OFF_WZOR, 32); cp(18, OFF_WZUO, 1024); cp(19, OFF_WYO, 3);
    cp(20, OFF_WYUO, 96);  cp(21, OFF_WUO, 32);
    cp(22, OFF_BY0, 3);  cp(23, OFF_BH0, 32); cp(24, OFF_B0, 32);  cp(25, OFF_BH1, 32);
    cp(26, OFF_BY1, 3);  cp(27, OFF_BZ1, 32); cp(28, OFF_B1, 32);  cp(29, OFF_BH2, 32);
    cp(30, OFF_BZ2, 32); cp(31, OFF_BY2, 3);  cp(32, OFF_B2, 32);  cp(33, OFF_BZO, 32);
    cp(34, OFF_BYO, 3);  cp(35, OFF_BOUT, 1);
    cp(36, OFF_FC1, 96); cp(37, OFF_FC1B, 32);
    cpT(38, OFF_FC2T);   cp(39, OFF_FC2B, 32);
    cpT(40, OFF_FC3T);   cp(41, OFF_FC3B, 32);
    cp(42, OFF_FC4, 32); cp(43, OFF_FC4B, 1);
  }
  __syncthreads();

  const int j = tid & 31;
  const int sample = blockIdx.x * 8 + (tid >> 5);
  const float* X = P.p[0] + sample * 6;
  const float q0 = X[0], q1 = X[1], q2 = X[2];
  const float y0 = X[3], y1 = X[4], y2 = X[5];
  const float yv[3] = {y0, y1, y2};

  // ---- t0 = q@w_yu0 + b_y0 (3-dim, q-only; dt0_k/dq_b = w_yu0[b][k]) ----
  float t0[3];
#pragma unroll
  for (int k = 0; k < 3; ++k)
    t0[k] = q0 * lds[OFF_WYU0 + k] + q1 * lds[OFF_WYU0 + 3 + k] + q2 * lds[OFF_WYU0 + 6 + k] +
            lds[OFF_BY0 + k];

  // ---- u1 = sp(q@w_h0 + b_h0) ----
  V4q u1;
  {
    float h = lds[OFF_BH0 + j] + q0 * lds[OFF_WH0 + j] + q1 * lds[OFF_WH0 + 32 + j] +
              q2 * lds[OFF_WH0 + 64 + j];
    float ss = sigf(h);
    u1.c[0] = spf(h);
    u1.c[1] = ss * lds[OFF_WH0 + j];
    u1.c[2] = ss * lds[OFF_WH0 + 32 + j];
    u1.c[3] = ss * lds[OFF_WH0 + 64 + j];
  }

  // ---- z1 = sp( (y*t0)@w_y0 + q@w_u0 + b_0 ) ----
  V22 z1;
  {
    V22 A;
    float wy[3] = {lds[OFF_WY0 + j], lds[OFF_WY0 + 32 + j], lds[OFF_WY0 + 64 + j]};
    float wu[3] = {lds[OFF_WU0 + j], lds[OFF_WU0 + 32 + j], lds[OFF_WU0 + 64 + j]};
    A.c[0] = lds[OFF_B0 + j] + (y0 * t0[0]) * wy[0] + (y1 * t0[1]) * wy[1] + (y2 * t0[2]) * wy[2] +
             q0 * wu[0] + q1 * wu[1] + q2 * wu[2];
#pragma unroll
    for (int a = 0; a < 3; ++a) A.c[1 + a] = t0[a] * wy[a];
#pragma unroll
    for (int b = 0; b < 3; ++b) {
      float acc = wu[b];
#pragma unroll
      for (int k = 0; k < 3; ++k) acc += yv[k] * lds[OFF_WYU0 + b * 3 + k] * wy[k];
      A.c[4 + b] = acc;
    }
#pragma unroll
    for (int t = 0; t < 6; ++t) A.c[7 + t] = 0.0f;
#pragma unroll
    for (int a = 0; a < 3; ++a)
#pragma unroll
      for (int b = 0; b < 3; ++b) A.c[13 + a * 3 + b] = lds[OFF_WYU0 + b * 3 + a] * wy[a];
    z1 = spchain22(A);
  }

  // ---- level 1 ----
  V4q h1 = {{lds[OFF_BH1 + j], 0, 0, 0}}, s1 = {{lds[OFF_BZ1 + j], 0, 0, 0}},
      w1 = {{lds[OFF_B1 + j], 0, 0, 0}};
  V4q t1[3];
#pragma unroll
  for (int m = 0; m < 3; ++m) { t1[m].c[0] = lds[OFF_BY1 + m]; t1[m].c[1] = t1[m].c[2] = t1[m].c[3] = 0.f; }
  stageU(lds, j, u1, OFF_WH1, OFF_WZU1, OFF_WU1, OFF_WYU1, h1, s1, w1, t1);
  V4q u2 = sp4(h1);
  {
    V22 p1 = prodZS(z1, s1);
    V22 A2;
    buildA(lds, j, yv, w1, t1, OFF_WY1, A2);
    mv22(lds, j, p1, OFF_WZ1R, A2);
    z1 = spchain22(A2);  // reuse z1 as z2
  }

  // ---- level 2 ----
  V4q h2 = {{lds[OFF_BH2 + j], 0, 0, 0}}, s2 = {{lds[OFF_BZ2 + j], 0, 0, 0}},
      w2 = {{lds[OFF_B2 + j], 0, 0, 0}};
  V4q t2[3];
#pragma unroll
  for (int m = 0; m < 3; ++m) { t2[m].c[0] = lds[OFF_BY2 + m]; t2[m].c[1] = t2[m].c[2] = t2[m].c[3] = 0.f; }
  stageU(lds, j, u2, OFF_WH2, OFF_WZU2, OFF_WU2, OFF_WYU2, h2, s2, w2, t2);
  V4q u3 = sp4(h2);
  {
    V22 p2 = prodZS(z1, s2);  // z1 currently holds z2
    V22 A3;
    buildA(lds, j, yv, w2, t2, OFF_WY2, A3);
    mv22(lds, j, p2, OFF_WZ2R, A3);
    z1 = spchain22(A3);  // reuse z1 as z3
  }

  // ---- level 3 (output stage pre-terms) ----
  V4q s3 = {{lds[OFF_BZO + j], 0, 0, 0}}, wo = {{0, 0, 0, 0}};
  V4q t3[3];
#pragma unroll
  for (int m = 0; m < 3; ++m) { t3[m].c[0] = lds[OFF_BYO + m]; t3[m].c[1] = t3[m].c[2] = t3[m].c[3] = 0.f; }
#pragma unroll 4
  for (int i = 0; i < 32; ++i) {
    float u0 = bc(u3.c[0], i), u1_ = bc(u3.c[1], i), u2_ = bc(u3.c[2], i), u3_ = bc(u3.c[3], i);
    float wz = lds[OFF_WZUO + i * 32 + j];
    s3.c[0] += u0 * wz; s3.c[1] += u1_ * wz; s3.c[2] += u2_ * wz; s3.c[3] += u3_ * wz;
    float wu = lds[OFF_WUO + i];
    wo.c[0] += u0 * wu; wo.c[1] += u1_ * wu; wo.c[2] += u2_ * wu; wo.c[3] += u3_ * wu;
#pragma unroll
    for (int m = 0; m < 3; ++m) {
      float wy = lds[OFF_WYUO + i * 3 + m];
      t3[m].c[0] += u0 * wy; t3[m].c[1] += u1_ * wy; t3[m].c[2] += u2_ * wy; t3[m].c[3] += u3_ * wy;
    }
  }

  // ---- V chain (q-only; only dq comps needed at the end) ----
  V4q V3;
  {
    float f0 = lds[OFF_FC1 + j * 3], f1 = lds[OFF_FC1 + j * 3 + 1], f2 = lds[OFF_FC1 + j * 3 + 2];
    float hp = lds[OFF_FC1B + j] + q0 * f0 + q1 * f1 + q2 * f2;
    V4q V1;
    float ss = sigf(hp);
    V1.c[0] = spf(hp); V1.c[1] = ss * f0; V1.c[2] = ss * f1; V1.c[3] = ss * f2;
    V4q Va = {{lds[OFF_FC2B + j], 0, 0, 0}};
#pragma unroll 4
    for (int i = 0; i < 32; ++i) {
      float wv = lds[OFF_FC2T + i * 32 + j];
      Va.c[0] += bc(V1.c[0], i) * wv; Va.c[1] += bc(V1.c[1], i) * wv;
      Va.c[2] += bc(V1.c[2], i) * wv; Va.c[3] += bc(V1.c[3], i) * wv;
    }
    V4q V2 = sp4(Va);
    V4q Vb = {{lds[OFF_FC3B + j], 0, 0, 0}};
#pragma unroll 4
    for (int i = 0; i < 32; ++i) {
      float wv = lds[OFF_FC3T + i * 32 + j];
      Vb.c[0] += bc(V2.c[0], i) * wv; Vb.c[1] += bc(V2.c[1], i) * wv;
      Vb.c[2] += bc(V2.c[2], i) * wv; Vb.c[3] += bc(V2.c[3], i) * wv;
    }
    V3 = sp4(Vb);
  }

  // ---- p3 = z3*s3, then reduce 25 jet comps over 32 lanes ----
  float red[25];
  {
    V22 p3 = prodZS(z1, s3);  // z1 holds z3
    float wz = lds[OFF_WZOR + j];
#pragma unroll
    for (int k = 0; k < 22; ++k) red[k] = p3.c[k] * wz;
    float f4 = lds[OFF_FC4 + j];
    red[22] = V3.c[1] * f4; red[23] = V3.c[2] * f4; red[24] = V3.c[3] * f4;
  }
#pragma unroll
  for (int m = 16; m >= 1; m >>= 1) {
#pragma unroll
    for (int k = 0; k < 25; ++k) red[k] += __shfl_xor(red[k], m, 32);
  }

  if (j == 0) {
    const float wyo[3] = {lds[OFF_WYO], lds[OFF_WYO + 1], lds[OFF_WYO + 2]};
    float Av = red[0] + wo.c[0] + lds[OFF_BOUT] + y0 * t3[0].c[0] * wyo[0] +
               y1 * t3[1].c[0] * wyo[1] + y2 * t3[2].c[0] * wyo[2];
    float Agy[3];
#pragma unroll
    for (int a = 0; a < 3; ++a) Agy[a] = red[1 + a] + t3[a].c[0] * wyo[a];
    float Agq[3];
#pragma unroll
    for (int b = 0; b < 3; ++b)
      Agq[b] = red[4 + b] + wo.c[1 + b] + y0 * t3[0].c[1 + b] * wyo[0] +
               y1 * t3[1].c[1 + b] * wyo[1] + y2 * t3[2].c[1 + b] * wyo[2];
    float s = sigf(Av), d = s * (1.0f - s);

    double Mm[3][3], Cm[3][3];
    const int pa[6] = {0, 0, 0, 1, 1, 2}, pb[6] = {0, 1, 2, 1, 2, 2};
#pragma unroll
    for (int t = 0; t < 6; ++t) {
      double m = (double)s * (double)red[7 + t] +
                 (double)d * (double)Agy[pa[t]] * (double)Agy[pb[t]];
      Mm[pa[t]][pb[t]] = m; Mm[pb[t]][pa[t]] = m;
    }
#pragma unroll
    for (int a = 0; a < 3; ++a)
#pragma unroll
      for (int b = 0; b < 3; ++b) {
        float ah = red[13 + a * 3 + b] + t3[a].c[1 + b] * wyo[a];
        Cm[a][b] = (double)s * (double)ah + (double)d * (double)Agy[a] * (double)Agq[b];
      }
    const double yd[3] = {(double)y0, (double)y1, (double)y2};
    double rr[3];
#pragma unroll
    for (int i2 = 0; i2 < 3; ++i2) {
      double g = (double)s * (double)Agq[i2] - (double)red[22 + i2];
      rr[i2] = g - (yd[0] * Cm[i2][0] + yd[1] * Cm[i2][1] + yd[2] * Cm[i2][2]);
    }
    double a = Mm[0][0], b_ = Mm[0][1], c_ = Mm[0][2], dd = Mm[1][1], e = Mm[1][2], f = Mm[2][2];
    double A00 = dd * f - e * e, A01 = c_ * e - b_ * f, A02 = b_ * e - c_ * dd;
    double A11 = a * f - c_ * c_, A12 = b_ * c_ - a * e, A22 = a * dd - b_ * b_;
    double det = a * A00 + b_ * A01 + c_ * A02;
    double idet = 1.0 / det;
    double d0 = (A00 * rr[0] + A01 * rr[1] + A02 * rr[2]) * idet;
    double d1 = (A01 * rr[0] + A11 * rr[1] + A12 * rr[2]) * idet;
    double d2 = (A02 * rr[0] + A12 * rr[1] + A22 * rr[2]) * idet;

    float* O = out + (size_t)sample * 6;
    O[0] = q0 + 0.001f * y0;
    O[1] = q1 + 0.001f * y1;
    O[2] = q2 + 0.001f * y2;
    O[3] = y0 + 0.001f * (float)d0;
    O[4] = y1 + 0.001f * (float)d1;
    O[5] = y2 + 0.001f * (float)d2;
  }
}

extern "C" void kernel_launch(void* const* d_in, const int* in_sizes, int n_in,
                              void* d_out, int out_size, void* d_ws, size_t ws_size,
                              hipStream_t stream) {
  (void)in_sizes; (void)n_in; (void)d_ws; (void)ws_size; (void)out_size;
  Ptrs P;
  for (int i = 0; i < 44; ++i) P.p[i] = (const float*)d_in[i];
  float* out = (float*)d_out;
  dim3 grid(B_TOTAL / 8), block(NTH);
  hipLaunchKernelGGL(lnn_step_kernel, grid, block, 0, stream, P, out);
}

// Round 2
// 386.067 us; speedup vs baseline: 1.1072x; 1.1072x over previous
//
#include <hip/hip_runtime.h>

#define NTH 256
#define B_TOTAL 32768

struct Ptrs { const float* p[44]; };

// input indices
enum : int {
  I_X = 0,
  I_WH0 = 1, I_WY0 = 2, I_WYU0 = 3, I_WU0 = 4,
  I_WH1 = 5, I_WZ1 = 6, I_WZU1 = 7, I_WY1 = 8, I_WYU1 = 9, I_WU1 = 10,
  I_WH2 = 11, I_WZ2 = 12, I_WZU2 = 13, I_WY2 = 14, I_WYU2 = 15, I_WU2 = 16,
  I_WZO = 17, I_WZUO = 18, I_WYO = 19, I_WYUO = 20, I_WUO = 21,
  I_BY0 = 22, I_BH0 = 23, I_B0 = 24, I_BH1 = 25, I_BY1 = 26, I_BZ1 = 27, I_B1 = 28,
  I_BH2 = 29, I_BZ2 = 30, I_BY2 = 31, I_B2 = 32, I_BZO = 33, I_BYO = 34, I_BOUT = 35,
  I_FC1 = 36, I_FC1B = 37, I_FC2 = 38, I_FC2B = 39, I_FC3 = 40, I_FC3B = 41,
  I_FC4 = 42, I_FC4B = 43
};

// jet: c[0]=v, c[1..3]=dy, c[4..6]=dq, c[7..12]=d2yy sym {00,01,02,11,12,22},
// c[13..21]=d2ydq [a*3+b]
struct V22 { float c[22]; };
struct V4q { float c[4]; };

__device__ __forceinline__ float spf(float x) {
  return fmaxf(x, 0.0f) + __logf(1.0f + __expf(-fabsf(x)));
}
__device__ __forceinline__ float sigf(float x) {
  return __fdividef(1.0f, 1.0f + __expf(-x));
}

__device__ __forceinline__ V22 spchain22(const V22& A) {
  V22 Z;
  float s = sigf(A.c[0]);
  float d = s * (1.0f - s);
  Z.c[0] = spf(A.c[0]);
#pragma unroll
  for (int a = 0; a < 3; ++a) Z.c[1 + a] = s * A.c[1 + a];
#pragma unroll
  for (int b = 0; b < 3; ++b) Z.c[4 + b] = s * A.c[4 + b];
  const int pa[6] = {0, 0, 0, 1, 1, 2}, pb[6] = {0, 1, 2, 1, 2, 2};
#pragma unroll
  for (int t = 0; t < 6; ++t)
    Z.c[7 + t] = s * A.c[7 + t] + d * A.c[1 + pa[t]] * A.c[1 + pb[t]];
#pragma unroll
  for (int a = 0; a < 3; ++a)
#pragma unroll
    for (int b = 0; b < 3; ++b)
      Z.c[13 + a * 3 + b] = s * A.c[13 + a * 3 + b] + d * A.c[1 + a] * A.c[4 + b];
  return Z;
}

__device__ __forceinline__ V4q sp4(const V4q& h) {
  V4q u;
  float ss = sigf(h.c[0]);
  u.c[0] = spf(h.c[0]);
  u.c[1] = ss * h.c[1];
  u.c[2] = ss * h.c[2];
  u.c[3] = ss * h.c[3];
  return u;
}

__device__ __forceinline__ V22 prodZS(const V22& Z, const V4q& S) {
  V22 P;
  P.c[0] = Z.c[0] * S.c[0];
#pragma unroll
  for (int a = 0; a < 3; ++a) P.c[1 + a] = S.c[0] * Z.c[1 + a];
#pragma unroll
  for (int b = 0; b < 3; ++b) P.c[4 + b] = Z.c[0] * S.c[1 + b] + S.c[0] * Z.c[4 + b];
#pragma unroll
  for (int t = 0; t < 6; ++t) P.c[7 + t] = S.c[0] * Z.c[7 + t];
#pragma unroll
  for (int a = 0; a < 3; ++a)
#pragma unroll
    for (int b = 0; b < 3; ++b)
      P.c[13 + a * 3 + b] = S.c[0] * Z.c[13 + a * 3 + b] + Z.c[1 + a] * S.c[1 + b];
  return P;
}

// write 22-comp jet (pad to 24) into LDS row (16B-aligned, stride 28 floats)
__device__ __forceinline__ void stage22(float* row, const V22& p) {
  *(float4*)(row + 0)  = make_float4(p.c[0], p.c[1], p.c[2], p.c[3]);
  *(float4*)(row + 4)  = make_float4(p.c[4], p.c[5], p.c[6], p.c[7]);
  *(float4*)(row + 8)  = make_float4(p.c[8], p.c[9], p.c[10], p.c[11]);
  *(float4*)(row + 12) = make_float4(p.c[12], p.c[13], p.c[14], p.c[15]);
  *(float4*)(row + 16) = make_float4(p.c[16], p.c[17], p.c[18], p.c[19]);
  *(float4*)(row + 20) = make_float4(p.c[20], p.c[21], 0.0f, 0.0f);
}

// acc[k] += sum_i pstage[i][k] * (relu?)W[i*32+j]   (W global, pstage LDS broadcast)
template <bool RELU>
__device__ __forceinline__ void mv22g(const float* __restrict__ W, int j,
                                      const float* ps, V22& acc) {
#pragma unroll 8
  for (int i = 0; i < 32; ++i) {
    float w = W[i * 32 + j];
    if (RELU) w = fmaxf(w, 0.0f);
    const float* r = ps + i * 28;
    float4 r0 = *(const float4*)(r + 0);
    float4 r1 = *(const float4*)(r + 4);
    float4 r2 = *(const float4*)(r + 8);
    float4 r3 = *(const float4*)(r + 12);
    float4 r4 = *(const float4*)(r + 16);
    float4 r5 = *(const float4*)(r + 20);
    acc.c[0] += r0.x * w;  acc.c[1] += r0.y * w;  acc.c[2] += r0.z * w;  acc.c[3] += r0.w * w;
    acc.c[4] += r1.x * w;  acc.c[5] += r1.y * w;  acc.c[6] += r1.z * w;  acc.c[7] += r1.w * w;
    acc.c[8] += r2.x * w;  acc.c[9] += r2.y * w;  acc.c[10] += r2.z * w; acc.c[11] += r2.w * w;
    acc.c[12] += r3.x * w; acc.c[13] += r3.y * w; acc.c[14] += r3.z * w; acc.c[15] += r3.w * w;
    acc.c[16] += r4.x * w; acc.c[17] += r4.y * w; acc.c[18] += r4.z * w; acc.c[19] += r4.w * w;
    acc.c[20] += r5.x * w; acc.c[21] += r5.y * w;
  }
}

// h += u@Wh, s += u@Wzu, w += u@Wu (global, col j), t[m] += u@Wyu (uniform s_load)
__device__ __forceinline__ void stageUg(const float* __restrict__ Wh,
                                        const float* __restrict__ Wzu,
                                        const float* __restrict__ Wu,
                                        const float* __restrict__ Wyu, int j,
                                        const float* us, V4q& h, V4q& s, V4q& w, V4q t[3]) {
#pragma unroll 8
  for (int i = 0; i < 32; ++i) {
    float4 u = *(const float4*)(us + i * 4);
    float wh = Wh[i * 32 + j], wz = Wzu[i * 32 + j], wu = Wu[i * 32 + j];
    h.c[0] += u.x * wh; h.c[1] += u.y * wh; h.c[2] += u.z * wh; h.c[3] += u.w * wh;
    s.c[0] += u.x * wz; s.c[1] += u.y * wz; s.c[2] += u.z * wz; s.c[3] += u.w * wz;
    w.c[0] += u.x * wu; w.c[1] += u.y * wu; w.c[2] += u.z * wu; w.c[3] += u.w * wu;
    float wy0 = Wyu[i * 3 + 0], wy1 = Wyu[i * 3 + 1], wy2 = Wyu[i * 3 + 2];
    t[0].c[0] += u.x * wy0; t[0].c[1] += u.y * wy0; t[0].c[2] += u.z * wy0; t[0].c[3] += u.w * wy0;
    t[1].c[0] += u.x * wy1; t[1].c[1] += u.y * wy1; t[1].c[2] += u.z * wy1; t[1].c[3] += u.w * wy1;
    t[2].c[0] += u.x * wy2; t[2].c[1] += u.y * wy2; t[2].c[2] += u.z * wy2; t[2].c[3] += u.w * wy2;
  }
}

// local (non-matvec) terms of a pre-activation: A = w + (y*t)@Wy, Wy (3,32) global
__device__ __forceinline__ void buildA(const float* __restrict__ Wy, int j, const float* yv,
                                       const V4q& w, const V4q t[3], V22& A) {
  float wy[3] = {Wy[j], Wy[32 + j], Wy[64 + j]};
  A.c[0] = w.c[0] + yv[0] * t[0].c[0] * wy[0] + yv[1] * t[1].c[0] * wy[1] + yv[2] * t[2].c[0] * wy[2];
#pragma unroll
  for (int a = 0; a < 3; ++a) A.c[1 + a] = t[a].c[0] * wy[a];
#pragma unroll
  for (int b = 0; b < 3; ++b)
    A.c[4 + b] = w.c[1 + b] + yv[0] * t[0].c[1 + b] * wy[0] + yv[1] * t[1].c[1 + b] * wy[1] +
                 yv[2] * t[2].c[1 + b] * wy[2];
#pragma unroll
  for (int t6 = 0; t6 < 6; ++t6) A.c[7 + t6] = 0.0f;
#pragma unroll
  for (int a = 0; a < 3; ++a)
#pragma unroll
    for (int b = 0; b < 3; ++b) A.c[13 + a * 3 + b] = t[a].c[1 + b] * wy[a];
}

// out = bias + V @ Wrow (Wrow = row j of a (32,32) matrix, dwordx4-preloaded)
__device__ __forceinline__ V4q vmat(const float* __restrict__ Wrow, const float* us, float bias) {
  float4 wr[8];
#pragma unroll
  for (int r = 0; r < 8; ++r) wr[r] = *(const float4*)(Wrow + r * 4);
  V4q a = {{bias, 0.f, 0.f, 0.f}};
#pragma unroll
  for (int i = 0; i < 32; ++i) {
    float4 u = *(const float4*)(us + i * 4);
    float w = ((const float*)wr)[i];  // compile-time index after full unroll
    a.c[0] += u.x * w; a.c[1] += u.y * w; a.c[2] += u.z * w; a.c[3] += u.w * w;
  }
  return a;
}

__global__ __launch_bounds__(NTH, 4) void lnn_step_kernel(Ptrs P, float* __restrict__ out) {
  // LDS: jet staging only. pstage row stride 28 floats -> per-phase bank
  // pattern 7j (coprime 32) = conflict-free writes; reads are uniform broadcasts.
  __shared__ float pstage[4][2][32][28];  // 28 KiB
  __shared__ float ustage[4][2][32][4];   // 4 KiB

  const int tid = threadIdx.x;
  const int j = tid & 31;
  const int half = (tid >> 5) & 1;
  const int wv = tid >> 6;
  const int sample = blockIdx.x * 8 + (tid >> 5);

  float* prow = &pstage[wv][half][0][0];
  float* urow = &ustage[wv][half][0][0];

  const float* X = P.p[I_X] + sample * 6;
  const float q0 = X[0], q1 = X[1], q2 = X[2];
  const float y0 = X[3], y1 = X[4], y2 = X[5];
  const float yv[3] = {y0, y1, y2};

  // ---------------- V chain first (lowest pressure); keep only dV/dq ----------------
  float Vg0, Vg1, Vg2;
  {
    const float* fc1 = P.p[I_FC1];
    float f0 = fc1[j * 3], f1 = fc1[j * 3 + 1], f2 = fc1[j * 3 + 2];
    float hp = P.p[I_FC1B][j] + q0 * f0 + q1 * f1 + q2 * f2;
    float ss = sigf(hp);
    *(float4*)(urow + j * 4) = make_float4(spf(hp), ss * f0, ss * f1, ss * f2);
    V4q Va = vmat(P.p[I_FC2] + j * 32, urow, P.p[I_FC2B][j]);
    V4q V2 = sp4(Va);
    *(float4*)(urow + j * 4) = make_float4(V2.c[0], V2.c[1], V2.c[2], V2.c[3]);
    V4q Vb = vmat(P.p[I_FC3] + j * 32, urow, P.p[I_FC3B][j]);
    V4q V3 = sp4(Vb);
    float f4 = P.p[I_FC4][j];
    Vg0 = V3.c[1] * f4; Vg1 = V3.c[2] * f4; Vg2 = V3.c[3] * f4;
  }

  // ---- t0 = q@w_yu0 + b_y0 (uniform s_loads) ----
  const float* yu0 = P.p[I_WYU0];
  float t0[3];
#pragma unroll
  for (int k = 0; k < 3; ++k)
    t0[k] = q0 * yu0[k] + q1 * yu0[3 + k] + q2 * yu0[6 + k] + P.p[I_BY0][k];

  // ---- u1 = sp(q@w_h0 + b_h0) ----
  V4q u1;
  {
    const float* wh0 = P.p[I_WH0];
    float w0 = wh0[j], w1 = wh0[32 + j], w2 = wh0[64 + j];
    float h = P.p[I_BH0][j] + q0 * w0 + q1 * w1 + q2 * w2;
    float ss = sigf(h);
    u1.c[0] = spf(h); u1.c[1] = ss * w0; u1.c[2] = ss * w1; u1.c[3] = ss * w2;
  }

  // ---- z1 = sp( (y*t0)@w_y0 + q@w_u0 + b_0 ) ----
  V22 z;
  {
    const float* Wy = P.p[I_WY0];
    const float* Wu = P.p[I_WU0];
    float wy[3] = {Wy[j], Wy[32 + j], Wy[64 + j]};
    float wu[3] = {Wu[j], Wu[32 + j], Wu[64 + j]};
    V22 A;
    A.c[0] = P.p[I_B0][j] + (y0 * t0[0]) * wy[0] + (y1 * t0[1]) * wy[1] + (y2 * t0[2]) * wy[2] +
             q0 * wu[0] + q1 * wu[1] + q2 * wu[2];
#pragma unroll
    for (int a = 0; a < 3; ++a) A.c[1 + a] = t0[a] * wy[a];
#pragma unroll
    for (int b = 0; b < 3; ++b) {
      float acc = wu[b];
#pragma unroll
      for (int k = 0; k < 3; ++k) acc += yv[k] * yu0[b * 3 + k] * wy[k];
      A.c[4 + b] = acc;
    }
#pragma unroll
    for (int t = 0; t < 6; ++t) A.c[7 + t] = 0.0f;
#pragma unroll
    for (int a = 0; a < 3; ++a)
#pragma unroll
      for (int b = 0; b < 3; ++b) A.c[13 + a * 3 + b] = yu0[b * 3 + a] * wy[a];
    z = spchain22(A);
  }

  // ---- level 1 ----
  V4q u2;
  {
    V4q h1 = {{P.p[I_BH1][j], 0, 0, 0}}, s1 = {{P.p[I_BZ1][j], 0, 0, 0}},
        w1 = {{P.p[I_B1][j], 0, 0, 0}};
    V4q t1[3];
#pragma unroll
    for (int m = 0; m < 3; ++m) { t1[m].c[0] = P.p[I_BY1][m]; t1[m].c[1] = t1[m].c[2] = t1[m].c[3] = 0.f; }
    *(float4*)(urow + j * 4) = make_float4(u1.c[0], u1.c[1], u1.c[2], u1.c[3]);
    stageUg(P.p[I_WH1], P.p[I_WZU1], P.p[I_WU1], P.p[I_WYU1], j, urow, h1, s1, w1, t1);
    u2 = sp4(h1);
    V22 p1 = prodZS(z, s1);
    V22 A2;
    buildA(P.p[I_WY1], j, yv, w1, t1, A2);
    stage22(prow + j * 28, p1);
    mv22g<true>(P.p[I_WZ1], j, prow, A2);
    z = spchain22(A2);  // z2
  }

  // ---- level 2 ----
  V4q u3;
  {
    V4q h2 = {{P.p[I_BH2][j], 0, 0, 0}}, s2 = {{P.p[I_BZ2][j], 0, 0, 0}},
        w2 = {{P.p[I_B2][j], 0, 0, 0}};
    V4q t2[3];
#pragma unroll
    for (int m = 0; m < 3; ++m) { t2[m].c[0] = P.p[I_BY2][m]; t2[m].c[1] = t2[m].c[2] = t2[m].c[3] = 0.f; }
    *(float4*)(urow + j * 4) = make_float4(u2.c[0], u2.c[1], u2.c[2], u2.c[3]);
    stageUg(P.p[I_WH2], P.p[I_WZU2], P.p[I_WU2], P.p[I_WYU2], j, urow, h2, s2, w2, t2);
    u3 = sp4(h2);
    V22 p2 = prodZS(z, s2);
    V22 A3;
    buildA(P.p[I_WY2], j, yv, w2, t2, A3);
    stage22(prow + j * 28, p2);
    mv22g<true>(P.p[I_WZ2], j, prow, A3);
    z = spchain22(A3);  // z3
  }

  // ---- level 3 (output-stage pre-terms) ----
  V4q s3 = {{P.p[I_BZO][j], 0, 0, 0}}, wo = {{0, 0, 0, 0}};
  V4q t3[3];
#pragma unroll
  for (int m = 0; m < 3; ++m) { t3[m].c[0] = P.p[I_BYO][m]; t3[m].c[1] = t3[m].c[2] = t3[m].c[3] = 0.f; }
  {
    const float* Wzuo = P.p[I_WZUO];
    const float* Wuo = P.p[I_WUO];
    const float* Wyuo = P.p[I_WYUO];
    *(float4*)(urow + j * 4) = make_float4(u3.c[0], u3.c[1], u3.c[2], u3.c[3]);
#pragma unroll 8
    for (int i = 0; i < 32; ++i) {
      float4 u = *(const float4*)(urow + i * 4);
      float wz = Wzuo[i * 32 + j];
      s3.c[0] += u.x * wz; s3.c[1] += u.y * wz; s3.c[2] += u.z * wz; s3.c[3] += u.w * wz;
      float wu = Wuo[i];  // uniform -> s_load
      wo.c[0] += u.x * wu; wo.c[1] += u.y * wu; wo.c[2] += u.z * wu; wo.c[3] += u.w * wu;
      float wy0 = Wyuo[i * 3], wy1 = Wyuo[i * 3 + 1], wy2 = Wyuo[i * 3 + 2];
      t3[0].c[0] += u.x * wy0; t3[0].c[1] += u.y * wy0; t3[0].c[2] += u.z * wy0; t3[0].c[3] += u.w * wy0;
      t3[1].c[0] += u.x * wy1; t3[1].c[1] += u.y * wy1; t3[1].c[2] += u.z * wy1; t3[1].c[3] += u.w * wy1;
      t3[2].c[0] += u.x * wy2; t3[2].c[1] += u.y * wy2; t3[2].c[2] += u.z * wy2; t3[2].c[3] += u.w * wy2;
    }
  }

  // ---- p3 = z3*s3, reduce 25 comps over 32 lanes ----
  float red[25];
  {
    V22 p3 = prodZS(z, s3);
    float wz = fmaxf(P.p[I_WZO][j], 0.0f);  // relu(w_z_out)
#pragma unroll
    for (int k = 0; k < 22; ++k) red[k] = p3.c[k] * wz;
    red[22] = Vg0; red[23] = Vg1; red[24] = Vg2;
  }
#pragma unroll
  for (int m = 16; m >= 1; m >>= 1) {
#pragma unroll
    for (int k = 0; k < 25; ++k) red[k] += __shfl_xor(red[k], m, 32);
  }

  if (j == 0) {
    const float* Wyo = P.p[I_WYO];
    const float wyo[3] = {Wyo[0], Wyo[1], Wyo[2]};
    float Av = red[0] + wo.c[0] + P.p[I_BOUT][0] + y0 * t3[0].c[0] * wyo[0] +
               y1 * t3[1].c[0] * wyo[1] + y2 * t3[2].c[0] * wyo[2];
    float Agy[3];
#pragma unroll
    for (int a = 0; a < 3; ++a) Agy[a] = red[1 + a] + t3[a].c[0] * wyo[a];
    float Agq[3];
#pragma unroll
    for (int b = 0; b < 3; ++b)
      Agq[b] = red[4 + b] + wo.c[1 + b] + y0 * t3[0].c[1 + b] * wyo[0] +
               y1 * t3[1].c[1 + b] * wyo[1] + y2 * t3[2].c[1 + b] * wyo[2];
    float s = sigf(Av), d = s * (1.0f - s);

    double Mm[3][3], Cm[3][3];
    const int pa[6] = {0, 0, 0, 1, 1, 2}, pb[6] = {0, 1, 2, 1, 2, 2};
#pragma unroll
    for (int t = 0; t < 6; ++t) {
      double m = (double)s * (double)red[7 + t] +
                 (double)d * (double)Agy[pa[t]] * (double)Agy[pb[t]];
      Mm[pa[t]][pb[t]] = m; Mm[pb[t]][pa[t]] = m;
    }
#pragma unroll
    for (int a = 0; a < 3; ++a)
#pragma unroll
      for (int b = 0; b < 3; ++b) {
        float ah = red[13 + a * 3 + b] + t3[a].c[1 + b] * wyo[a];
        Cm[a][b] = (double)s * (double)ah + (double)d * (double)Agy[a] * (double)Agq[b];
      }
    const double yd[3] = {(double)y0, (double)y1, (double)y2};
    double rr[3];
#pragma unroll
    for (int i2 = 0; i2 < 3; ++i2) {
      double g = (double)s * (double)Agq[i2] - (double)red[22 + i2];
      rr[i2] = g - (yd[0] * Cm[i2][0] + yd[1] * Cm[i2][1] + yd[2] * Cm[i2][2]);
    }
    double a = Mm[0][0], b_ = Mm[0][1], c_ = Mm[0][2], dd = Mm[1][1], e = Mm[1][2], f = Mm[2][2];
    double A00 = dd * f - e * e, A01 = c_ * e - b_ * f, A02 = b_ * e - c_ * dd;
    double A11 = a * f - c_ * c_, A12 = b_ * c_ - a * e, A22 = a * dd - b_ * b_;
    double det = a * A00 + b_ * A01 + c_ * A02;
    double idet = 1.0 / det;
    double d0 = (A00 * rr[0] + A01 * rr[1] + A02 * rr[2]) * idet;
    double d1 = (A01 * rr[0] + A11 * rr[1] + A12 * rr[2]) * idet;
    double d2 = (A02 * rr[0] + A12 * rr[1] + A22 * rr[2]) * idet;

    float* O = out + (size_t)sample * 6;
    O[0] = q0 + 0.001f * y0;
    O[1] = q1 + 0.001f * y1;
    O[2] = q2 + 0.001f * y2;
    O[3] = y0 + 0.001f * (float)d0;
    O[4] = y1 + 0.001f * (float)d1;
    O[5] = y2 + 0.001f * (float)d2;
  }
}

extern "C" void kernel_launch(void* const* d_in, const int* in_sizes, int n_in,
                              void* d_out, int out_size, void* d_ws, size_t ws_size,
                              hipStream_t stream) {
  (void)in_sizes; (void)n_in; (void)d_ws; (void)ws_size; (void)out_size;
  Ptrs P;
  for (int i = 0; i < 44; ++i) P.p[i] = (const float*)d_in[i];
  float* out = (float*)d_out;
  dim3 grid(B_TOTAL / 8), block(NTH);
  hipLaunchKernelGGL(lnn_step_kernel, grid, block, 0, stream, P, out);
}